// Round 1
// baseline (1052.787 us; speedup 1.0000x reference)
//
#include <hip/hip_runtime.h>

// SparseGapPerSpecies via quadratic-form restructuring:
//   e_atom[n] = (x_n^T M_{s(n)} x_n) / ||x_n||^2,   M_s = sum_m (w_m/||y_m||^2) y_m y_m^T
// then energy[struct] = segment_sum(e_atom).
// FLOPs: 5.24e10 (vs 4.1e11 reference), no K-matrix materialization.

#define NFEAT 512
#define NSPEC 4

// ---- main qform tile params ----
#define QBM 128   // atoms per block
#define QBN 128   // output dims per block
#define QKT 32    // k-tile
#define ASTR 36   // LDS row stride (floats) for A tile: 36*4=144B, 16B-aligned, bank-spread

// ---------------- zero out + counters ----------------
__launch_bounds__(256)
__global__ void k_zero(float* out, int ns, int* run) {
    int i = blockIdx.x * 256 + threadIdx.x;
    if (i < ns) out[i] = 0.0f;
    if (i < NSPEC) run[i] = 0;
}

// ---------------- row inv-norms (one wave per 512-float row) ----------------
// dst[r] = (numer ? numer[r] : 1.0f) / ||row_r||^2
__launch_bounds__(256)
__global__ void k_rownorm(const float* __restrict__ rowsrc, const float* __restrict__ numer,
                          float* __restrict__ dst, int rows) {
    int wv = (blockIdx.x * 256 + threadIdx.x) >> 6;
    int lane = threadIdx.x & 63;
    if (wv >= rows) return;
    const float4* r = (const float4*)(rowsrc + (size_t)wv * NFEAT);
    float4 v0 = r[lane];
    float4 v1 = r[lane + 64];
    float s = v0.x * v0.x + v0.y * v0.y + v0.z * v0.z + v0.w * v0.w
            + v1.x * v1.x + v1.y * v1.y + v1.z * v1.z + v1.w * v1.w;
#pragma unroll
    for (int m = 1; m < 64; m <<= 1) s += __shfl_xor(s, m);
    if (lane == 0) dst[wv] = (numer ? numer[wv] : 1.0f) / s;
}

// ---------------- bucket atoms by species ----------------
__launch_bounds__(256)
__global__ void k_scatter(const int* __restrict__ species, int* __restrict__ run,
                          int* __restrict__ perm, int N) {
    __shared__ int lcnt[NSPEC];
    __shared__ int lbase[NSPEC];
    int t = threadIdx.x;
    if (t < NSPEC) lcnt[t] = 0;
    __syncthreads();
    int n = blockIdx.x * 256 + t;
    int s = 0, li = 0;
    bool valid = (n < N);
    if (valid) {
        s = species[n];
        li = atomicAdd(&lcnt[s], 1);
    }
    __syncthreads();
    if (t < NSPEC) lbase[t] = atomicAdd(&run[t], lcnt[t]);
    __syncthreads();
    if (valid) perm[(size_t)s * N + lbase[s] + li] = n;
}

// ---------------- M_s = A^T diag(wn) A  (A = support_points[s], 1000x512) ----------------
#define MK 16
__launch_bounds__(256)
__global__ void k_computeM(const float* __restrict__ sp, const float* __restrict__ wn,
                           float* __restrict__ Mmat, int Msup) {
    const int s = blockIdx.z;
    const int i0 = blockIdx.y * 64;
    const int j0 = blockIdx.x * 64;
    __shared__ __align__(16) float As[MK * 64];
    __shared__ __align__(16) float Bs[MK * 64];
    const float* A = sp + (size_t)s * Msup * NFEAT;
    const float* wv = wn + s * Msup;
    const int t = threadIdx.x;
    const int tx = t & 15, ty = t >> 4;
    float acc[4][4] = {{0.f}};
    for (int m0 = 0; m0 < Msup; m0 += MK) {
        __syncthreads();
#pragma unroll
        for (int it = 0; it < 4; ++it) {
            int kt = (t >> 6) * 4 + it;
            int c = t & 63;
            int m = m0 + kt;
            float av = 0.f, bv = 0.f;
            if (m < Msup) {
                av = A[(size_t)m * NFEAT + i0 + c];
                bv = A[(size_t)m * NFEAT + j0 + c] * wv[m];
            }
            As[kt * 64 + c] = av;
            Bs[kt * 64 + c] = bv;
        }
        __syncthreads();
#pragma unroll
        for (int kt = 0; kt < MK; ++kt) {
            float4 a = *(const float4*)&As[kt * 64 + ty * 4];
            float4 b = *(const float4*)&Bs[kt * 64 + tx * 4];
            float aa[4] = {a.x, a.y, a.z, a.w};
            float bb[4] = {b.x, b.y, b.z, b.w};
#pragma unroll
            for (int i = 0; i < 4; ++i)
#pragma unroll
                for (int j = 0; j < 4; ++j) acc[i][j] += aa[i] * bb[j];
        }
    }
    float* C = Mmat + (size_t)s * NFEAT * NFEAT;
#pragma unroll
    for (int i = 0; i < 4; ++i) {
        float4 v = {acc[i][0], acc[i][1], acc[i][2], acc[i][3]};
        *(float4*)(C + (size_t)(i0 + ty * 4 + i) * NFEAT + j0 + tx * 4) = v;
    }
}

// ---------------- main: per-species quadratic form + segment-sum ----------------
// Block: 128 atoms x 128 output dims, full k=512 loop; 256 threads, 8x8 micro-tile.
// Epilogue: e_partial = rowsum(acc * x), shfl-reduce over tx, atomicAdd into out[sid].
__launch_bounds__(256, 2)
__global__ void k_qform(const float* __restrict__ X, const float* __restrict__ Mmat,
                        const int* __restrict__ perm, const int* __restrict__ run,
                        const float* __restrict__ ninv, const int* __restrict__ sid,
                        float* __restrict__ out, int N) {
    const int s = blockIdx.z;
    const int cnt = run[s];
    const int p0 = blockIdx.x * QBM;
    if (p0 >= cnt) return;
    const int jt = blockIdx.y;

    __shared__ int aid[QBM];
    __shared__ __align__(16) float As[QBM * ASTR];
    __shared__ __align__(16) float Bs[QKT * QBN];

    const int t = threadIdx.x;
    if (t < QBM) {
        int p = p0 + t;
        aid[t] = (p < cnt) ? perm[(size_t)s * N + p] : -1;
    }
    __syncthreads();
    const int a0 = aid[0];

    const float* Ms = Mmat + (size_t)s * NFEAT * NFEAT + jt * QBN;

    float acc[8][8];
#pragma unroll
    for (int i = 0; i < 8; ++i)
#pragma unroll
        for (int j = 0; j < 8; ++j) acc[i][j] = 0.f;

    const int tx = t & 15, ty = t >> 4;

    for (int k0 = 0; k0 < NFEAT; k0 += QKT) {
        __syncthreads();
        // stage A: 128 atoms x 32 k  (1024 float4, 4 per thread)
#pragma unroll
        for (int it = 0; it < 4; ++it) {
            int idx = t + it * 256;
            int a = idx >> 3, kq = idx & 7;
            int id = aid[a];
            id = (id < 0) ? a0 : id;
            float4 v = *(const float4*)(X + (size_t)id * NFEAT + k0 + kq * 4);
            *(float4*)&As[a * ASTR + kq * 4] = v;
        }
        // stage B: 32 k x 128 dims  (1024 float4, 4 per thread), coalesced
#pragma unroll
        for (int it = 0; it < 4; ++it) {
            int idx = t + it * 256;
            int kt = idx >> 5, jq = idx & 31;
            float4 v = *(const float4*)(Ms + (size_t)(k0 + kt) * NFEAT + jq * 4);
            *(float4*)&Bs[kt * QBN + jq * 4] = v;
        }
        __syncthreads();
#pragma unroll
        for (int kq = 0; kq < 8; ++kq) {
            float4 av[8];
#pragma unroll
            for (int i = 0; i < 8; ++i) {
                int a = (i < 4) ? (ty * 4 + i) : (64 + ty * 4 + (i - 4));
                av[i] = *(const float4*)&As[a * ASTR + kq * 4];
            }
#pragma unroll
            for (int kk = 0; kk < 4; ++kk) {
                int k = kq * 4 + kk;
                float4 b0 = *(const float4*)&Bs[k * QBN + tx * 4];
                float4 b1 = *(const float4*)&Bs[k * QBN + 64 + tx * 4];
                float bb[8] = {b0.x, b0.y, b0.z, b0.w, b1.x, b1.y, b1.z, b1.w};
#pragma unroll
                for (int i = 0; i < 8; ++i) {
                    float a = (&av[i].x)[kk];
#pragma unroll
                    for (int j = 0; j < 8; ++j) acc[i][j] += a * bb[j];
                }
            }
        }
    }

    // epilogue: ep[i] = sum_j acc[i][j] * x[atom_i][dim_j]
    float ep[8];
#pragma unroll
    for (int i = 0; i < 8; ++i) {
        int a = (i < 4) ? (ty * 4 + i) : (64 + ty * 4 + (i - 4));
        int id = aid[a];
        int idc = (id < 0) ? a0 : id;
        const float* xr = X + (size_t)idc * NFEAT + jt * QBN;
        float4 x0 = *(const float4*)(xr + tx * 4);
        float4 x1 = *(const float4*)(xr + 64 + tx * 4);
        float xv[8] = {x0.x, x0.y, x0.z, x0.w, x1.x, x1.y, x1.z, x1.w};
        float e = 0.f;
#pragma unroll
        for (int j = 0; j < 8; ++j) e += acc[i][j] * xv[j];
        ep[i] = e;
    }
#pragma unroll
    for (int m = 1; m < 16; m <<= 1) {
#pragma unroll
        for (int i = 0; i < 8; ++i) ep[i] += __shfl_xor(ep[i], m);
    }
    if (tx == 0) {
#pragma unroll
        for (int i = 0; i < 8; ++i) {
            int a = (i < 4) ? (ty * 4 + i) : (64 + ty * 4 + (i - 4));
            int id = aid[a];
            if (id >= 0) atomicAdd(&out[sid[id]], ep[i] * ninv[id]);
        }
    }
}

extern "C" void kernel_launch(void* const* d_in, const int* in_sizes, int n_in,
                              void* d_out, int out_size, void* d_ws, size_t ws_size,
                              hipStream_t stream) {
    const float* ps      = (const float*)d_in[0];  // [N, 512]
    const float* sp      = (const float*)d_in[1];  // [4, 1000, 512]
    const float* w       = (const float*)d_in[2];  // [4, 1000]
    const int*   species = (const int*)d_in[3];    // [N]
    const int*   sid     = (const int*)d_in[4];    // [N] sorted
    float* out = (float*)d_out;                    // [n_struct]

    const int S    = NSPEC;
    const int F    = in_sizes[1] / in_sizes[2];    // 512
    const int Msup = in_sizes[2] / S;              // 1000
    const int N    = in_sizes[0] / F;              // 100000
    const int NS   = out_size;                     // 2000

    // workspace layout (all 4B types; d_ws is 256B-aligned)
    float* Mmat = (float*)d_ws;                    // S*F*F floats (4 MB)
    float* wn   = Mmat + (size_t)S * F * F;        // S*Msup floats
    float* ninv = wn + (size_t)S * Msup;           // N floats
    int*   run  = (int*)(ninv + N);                // NSPEC counters (+pad)
    int*   perm = run + 8;                         // S*N ints (segmented, stride N)

    (void)n_in; (void)ws_size;

    k_zero<<<dim3((NS + 255) / 256), dim3(256), 0, stream>>>(out, NS, run);
    k_rownorm<<<dim3((S * Msup + 3) / 4), dim3(256), 0, stream>>>(sp, w, wn, S * Msup);
    k_rownorm<<<dim3((N + 3) / 4), dim3(256), 0, stream>>>(ps, nullptr, ninv, N);
    k_scatter<<<dim3((N + 255) / 256), dim3(256), 0, stream>>>(species, run, perm, N);
    k_computeM<<<dim3(F / 64, F / 64, S), dim3(256), 0, stream>>>(sp, wn, Mmat, Msup);
    k_qform<<<dim3((N + QBM - 1) / QBM, F / QBN, S), dim3(256), 0, stream>>>(
        ps, Mmat, perm, run, ninv, sid, out, N);
}

// Round 4
// 647.661 us; speedup vs baseline: 1.6255x; 1.6255x over previous
//
#include <hip/hip_runtime.h>
#include <stdint.h>

// SparseGapPerSpecies:
//   e_atom[n] = (x_n^T M_{s(n)} x_n) / ||x_n||^2,  M_s = sum_m (w_m/||y_m||^2) y_m y_m^T
//   energy[struct] = segment_sum(e_atom)
// v3: split-fp16 MFMA bilinear evaluation (3 products, lo-scaled by 2048).
//   - __fp16 vector types (matches cvt_pkrtz / mfma builtin signatures).
//   - M pre-split into fp16 hi/lo, stored XOR-swizzled in global so global_load_lds
//     staging is a linear copy and ds_read_b128 A-frags are conflict-free.
//   - Wave holds 32 atoms' full rows as fp16 hi/lo B-frags in registers (X read once).
//   - Per 32-row k-slice: Z = M_slice * x^T via mfma_f32_32x32x16_f16 (3 chains),
//     folded into e against xc extracted from B-frag registers (shfl_xor(32) + select).

#define NFEAT 512
#define NSPEC 4
#define QAB 128   // atoms per qform block (4 waves x 32)

typedef __fp16 half8 __attribute__((ext_vector_type(8)));
typedef __fp16 half2t __attribute__((ext_vector_type(2)));
typedef float f32x16 __attribute__((ext_vector_type(16)));

#define AS1 __attribute__((address_space(1)))
#define AS3 __attribute__((address_space(3)))

static __device__ __forceinline__ void gload_lds16(const void* g, void* l) {
    __builtin_amdgcn_global_load_lds((const AS1 uint32_t*)g, (AS3 uint32_t*)l, 16, 0, 0);
}

union H2I { half2t h; int i; };
union H8V { half2t h2[4]; half8 h8; int4 i4; };

// ---------------- zero out + counters ----------------
__launch_bounds__(256)
__global__ void k_zero(float* out, int ns, int* run) {
    int i = blockIdx.x * 256 + threadIdx.x;
    if (i < ns) out[i] = 0.0f;
    if (i < NSPEC) run[i] = 0;
}

// ---------------- row inv-norm-weights for support points ----------------
// dst[r] = numer[r] / ||row_r||^2
__launch_bounds__(256)
__global__ void k_rownorm(const float* __restrict__ rowsrc, const float* __restrict__ numer,
                          float* __restrict__ dst, int rows) {
    int wv = (blockIdx.x * 256 + threadIdx.x) >> 6;
    int lane = threadIdx.x & 63;
    if (wv >= rows) return;
    const float4* r = (const float4*)(rowsrc + (size_t)wv * NFEAT);
    float4 v0 = r[lane];
    float4 v1 = r[lane + 64];
    float s = v0.x * v0.x + v0.y * v0.y + v0.z * v0.z + v0.w * v0.w
            + v1.x * v1.x + v1.y * v1.y + v1.z * v1.z + v1.w * v1.w;
#pragma unroll
    for (int m = 1; m < 64; m <<= 1) s += __shfl_xor(s, m);
    if (lane == 0) dst[wv] = numer[wv] / s;
}

// ---------------- bucket atoms by species ----------------
__launch_bounds__(256)
__global__ void k_scatter(const int* __restrict__ species, int* __restrict__ run,
                          int* __restrict__ perm, int N) {
    __shared__ int lcnt[NSPEC];
    __shared__ int lbase[NSPEC];
    int t = threadIdx.x;
    if (t < NSPEC) lcnt[t] = 0;
    __syncthreads();
    int n = blockIdx.x * 256 + t;
    int s = 0, li = 0;
    bool valid = (n < N);
    if (valid) {
        s = species[n];
        li = atomicAdd(&lcnt[s], 1);
    }
    __syncthreads();
    if (t < NSPEC) lbase[t] = atomicAdd(&run[t], lcnt[t]);
    __syncthreads();
    if (valid) perm[(size_t)s * N + lbase[s] + li] = n;
}

// ---------------- M_s = A^T diag(wn) A, written as swizzled fp16 hi/lo ----------------
// element (row,j) at byte: row*1024 + (((j>>3) ^ (row&7))<<4) + (j&7)*2
#define MK 16
__launch_bounds__(256)
__global__ void k_computeM(const float* __restrict__ sp, const float* __restrict__ wn,
                           __fp16* __restrict__ Mh, __fp16* __restrict__ Ml, int Msup) {
    const int s = blockIdx.z;
    const int i0 = blockIdx.y * 64;
    const int j0 = blockIdx.x * 64;
    __shared__ __align__(16) float As[MK * 64];
    __shared__ __align__(16) float Bs[MK * 64];
    const float* A = sp + (size_t)s * Msup * NFEAT;
    const float* wv = wn + s * Msup;
    const int t = threadIdx.x;
    const int tx = t & 15, ty = t >> 4;
    float acc[4][4] = {{0.f}};
    for (int m0 = 0; m0 < Msup; m0 += MK) {
        __syncthreads();
#pragma unroll
        for (int it = 0; it < 4; ++it) {
            int kt = (t >> 6) * 4 + it;
            int c = t & 63;
            int m = m0 + kt;
            float av = 0.f, bv = 0.f;
            if (m < Msup) {
                av = A[(size_t)m * NFEAT + i0 + c];
                bv = A[(size_t)m * NFEAT + j0 + c] * wv[m];
            }
            As[kt * 64 + c] = av;
            Bs[kt * 64 + c] = bv;
        }
        __syncthreads();
#pragma unroll
        for (int kt = 0; kt < MK; ++kt) {
            float4 a = *(const float4*)&As[kt * 64 + ty * 4];
            float4 b = *(const float4*)&Bs[kt * 64 + tx * 4];
            float aa[4] = {a.x, a.y, a.z, a.w};
            float bb[4] = {b.x, b.y, b.z, b.w};
#pragma unroll
            for (int i = 0; i < 4; ++i)
#pragma unroll
                for (int j = 0; j < 4; ++j) acc[i][j] += aa[i] * bb[j];
        }
    }
    const size_t base = (size_t)s * NFEAT * NFEAT;  // elements
    char* Hq = (char*)(Mh + base);
    char* Lq = (char*)(Ml + base);
#pragma unroll
    for (int i = 0; i < 4; ++i) {
        int row = i0 + ty * 4 + i;
        int jst = j0 + tx * 4;
        float a0 = acc[i][0], a1 = acc[i][1], a2 = acc[i][2], a3 = acc[i][3];
        half2t h01 = __builtin_amdgcn_cvt_pkrtz(a0, a1);
        half2t h23 = __builtin_amdgcn_cvt_pkrtz(a2, a3);
        float r0 = (a0 - (float)h01[0]) * 2048.f;
        float r1 = (a1 - (float)h01[1]) * 2048.f;
        float r2 = (a2 - (float)h23[0]) * 2048.f;
        float r3 = (a3 - (float)h23[1]) * 2048.f;
        half2t l01 = __builtin_amdgcn_cvt_pkrtz(r0, r1);
        half2t l23 = __builtin_amdgcn_cvt_pkrtz(r2, r3);
        int slot = (jst >> 3) ^ (row & 7);
        size_t off = (size_t)row * 1024 + (size_t)(slot << 4) + (size_t)((jst & 4) * 2);
        H2I c0, c1, c2, c3;
        c0.h = h01; c1.h = h23; c2.h = l01; c3.h = l23;
        int2 hv; hv.x = c0.i; hv.y = c1.i;
        int2 lv; lv.x = c2.i; lv.y = c3.i;
        *(int2*)(Hq + off) = hv;
        *(int2*)(Lq + off) = lv;
    }
}

// ---------------- main: split-fp16 MFMA bilinear form ----------------
__launch_bounds__(256, 1)
__global__ void k_qform(const float* __restrict__ X,
                        const __fp16* __restrict__ Mh, const __fp16* __restrict__ Ml,
                        const int* __restrict__ perm, const int* __restrict__ run,
                        const int* __restrict__ sid,
                        float* __restrict__ out, int N) {
    const int s = blockIdx.z;
    const int cnt = run[s];
    const int p0 = blockIdx.x * QAB;
    if (p0 >= cnt) return;
    __shared__ __align__(16) char lds[131072];  // [2][64 KB]: {Mh 32K, Ml 32K} per buffer

    const int t = threadIdx.x;
    const int w = t >> 6;
    const int l = t & 63;
    const int la = l & 31;   // atom lane / M row lane
    const int g = l >> 5;    // half-group

    int p = p0 + w * 32 + la;
    bool valid = (p < cnt);
    int pc = valid ? p : (cnt - 1);
    int id = perm[(size_t)s * N + pc];
    const float* xrow = X + (size_t)id * NFEAT;

    const char* mh_base = (const char*)(Mh + (size_t)s * NFEAT * NFEAT);
    const char* ml_base = (const char*)(Ml + (size_t)s * NFEAT * NFEAT);

    // ---- issue staging of k-slice `ks` into buffer `buf` ----
#define STAGE(buf, ks) { \
    const char* gh_ = mh_base + (ks) * 32768; \
    const char* gl_ = ml_base + (ks) * 32768; \
    char* lb_ = lds + (buf) * 65536; \
    _Pragma("unroll") \
    for (int i_ = 0; i_ < 8; ++i_) { \
        int off_ = w * 8192 + i_ * 1024; \
        gload_lds16(gh_ + off_ + l * 16, lb_ + off_); \
        gload_lds16(gl_ + off_ + l * 16, lb_ + 32768 + off_); \
    } }

    STAGE(0, 0)

    // ---- load this lane's x data: j = jh*16 + 8g + e (e=0..7), build fp16 hi/lo frags ----
    half8 xbh[32], xbl[32];
    float nrm = 0.f;
#pragma unroll
    for (int jh = 0; jh < 32; ++jh) {
        const float4* pA = (const float4*)(xrow + jh * 16 + g * 8);
        float4 v0 = pA[0], v1 = pA[1];
        float xv[8] = {v0.x, v0.y, v0.z, v0.w, v1.x, v1.y, v1.z, v1.w};
        H8V uh, ul;
#pragma unroll
        for (int q = 0; q < 4; ++q) {
            float a = xv[2 * q], b = xv[2 * q + 1];
            half2t hp = __builtin_amdgcn_cvt_pkrtz(a, b);
            float ra = (a - (float)hp[0]) * 2048.f;
            float rb = (b - (float)hp[1]) * 2048.f;
            half2t lp = __builtin_amdgcn_cvt_pkrtz(ra, rb);
            uh.h2[q] = hp; ul.h2[q] = lp;
            nrm += a * a + b * b;
        }
        xbh[jh] = uh.h8;
        xbl[jh] = ul.h8;
    }

    float ebuf = 0.f;
    __syncthreads();  // staging of slice 0 complete (vmcnt(0) drained before barrier)

#pragma unroll
    for (int ks = 0; ks < 16; ++ks) {
        if (ks < 15) STAGE((ks + 1) & 1, ks + 1)

        // ---- xc: x[a][32*ks + rowpat(r) + 4g] from B-frag registers ----
        // rowpat(r) = (r&3) + 8*(r>>2); own regs cover offsets {8g..8g+7, 16+8g..16+8g+7}
        H8V u0h, u0l, u1h, u1l;
        u0h.h8 = xbh[2 * ks];     u0l.h8 = xbl[2 * ks];
        u1h.h8 = xbh[2 * ks + 1]; u1l.h8 = xbl[2 * ks + 1];
        int4 F0h = u0h.i4, F0l = u0l.i4, F1h = u1h.i4, F1l = u1l.i4;
        int s0h0 = __shfl_xor(F0h.x, 32), s0h1 = __shfl_xor(F0h.y, 32);
        int s0h2 = __shfl_xor(F0h.z, 32), s0h3 = __shfl_xor(F0h.w, 32);
        int s0l0 = __shfl_xor(F0l.x, 32), s0l1 = __shfl_xor(F0l.y, 32);
        int s0l2 = __shfl_xor(F0l.z, 32), s0l3 = __shfl_xor(F0l.w, 32);
        int s1h0 = __shfl_xor(F1h.x, 32), s1h1 = __shfl_xor(F1h.y, 32);
        int s1h2 = __shfl_xor(F1h.z, 32), s1h3 = __shfl_xor(F1h.w, 32);
        int s1l0 = __shfl_xor(F1l.x, 32), s1l1 = __shfl_xor(F1l.y, 32);
        int s1l2 = __shfl_xor(F1l.z, 32), s1l3 = __shfl_xor(F1l.w, 32);
        bool hi = (g != 0);
        int Qa0h = hi ? s0h2 : F0h.x, Qb0h = hi ? s0h3 : F0h.y;
        int Qc0h = hi ? F0h.z : s0h0, Qd0h = hi ? F0h.w : s0h1;
        int Qa0l = hi ? s0l2 : F0l.x, Qb0l = hi ? s0l3 : F0l.y;
        int Qc0l = hi ? F0l.z : s0l0, Qd0l = hi ? F0l.w : s0l1;
        int Qa1h = hi ? s1h2 : F1h.x, Qb1h = hi ? s1h3 : F1h.y;
        int Qc1h = hi ? F1h.z : s1h0, Qd1h = hi ? F1h.w : s1h1;
        int Qa1l = hi ? s1l2 : F1l.x, Qb1l = hi ? s1l3 : F1l.y;
        int Qc1l = hi ? F1l.z : s1l0, Qd1l = hi ? F1l.w : s1l1;
        float xc[16];
#define XC2(QH, QL, o0, o1) { H2I qh_, ql_; qh_.i = (QH); ql_.i = (QL); \
        xc[o0] = (float)qh_.h[0] + (float)ql_.h[0] * (1.f/2048.f); \
        xc[o1] = (float)qh_.h[1] + (float)ql_.h[1] * (1.f/2048.f); }
        XC2(Qa0h, Qa0l, 0, 1)   XC2(Qb0h, Qb0l, 2, 3)
        XC2(Qc0h, Qc0l, 4, 5)   XC2(Qd0h, Qd0l, 6, 7)
        XC2(Qa1h, Qa1l, 8, 9)   XC2(Qb1h, Qb1l, 10, 11)
        XC2(Qc1h, Qc1l, 12, 13) XC2(Qd1h, Qd1l, 14, 15)
#undef XC2

        // ---- Z = M_slice * x^T over all j, 3 separate accumulator chains ----
        const char* mb = lds + (ks & 1) * 65536;
        f32x16 z0 = {}, z1 = {}, z2 = {};
#pragma unroll
        for (int jh = 0; jh < 32; ++jh) {
            int slot = (2 * jh + g) ^ (la & 7);
            int boff = la * 1024 + slot * 16;
            half8 Ah = *(const half8*)(mb + boff);
            half8 Al = *(const half8*)(mb + 32768 + boff);
            z0 = __builtin_amdgcn_mfma_f32_32x32x16_f16(Ah, xbh[jh], z0, 0, 0, 0);
            z1 = __builtin_amdgcn_mfma_f32_32x32x16_f16(Ah, xbl[jh], z1, 0, 0, 0);
            z2 = __builtin_amdgcn_mfma_f32_32x32x16_f16(Al, xbh[jh], z2, 0, 0, 0);
        }
        // ---- fold ----
#pragma unroll
        for (int r = 0; r < 16; ++r) {
            float z = z0[r] + (z1[r] + z2[r]) * (1.f / 2048.f);
            ebuf = fmaf(xc[r], z, ebuf);
        }
        __syncthreads();  // drains staging (vmcnt 0) + protects buffer swap
    }

    // ---- epilogue: combine lane halves, normalize, segment-sum ----
    float ef = ebuf + __shfl_xor(ebuf, 32);
    float nf = nrm + __shfl_xor(nrm, 32);
    if (g == 0 && valid) {
        atomicAdd(&out[sid[id]], ef / nf);
    }
#undef STAGE
}

extern "C" void kernel_launch(void* const* d_in, const int* in_sizes, int n_in,
                              void* d_out, int out_size, void* d_ws, size_t ws_size,
                              hipStream_t stream) {
    const float* ps      = (const float*)d_in[0];  // [N, 512]
    const float* sp      = (const float*)d_in[1];  // [4, 1000, 512]
    const float* w       = (const float*)d_in[2];  // [4, 1000]
    const int*   species = (const int*)d_in[3];    // [N]
    const int*   sid     = (const int*)d_in[4];    // [N]
    float* out = (float*)d_out;                    // [n_struct]

    const int S    = NSPEC;
    const int F    = NFEAT;
    const int Msup = in_sizes[2] / S;              // 1000
    const int N    = in_sizes[0] / F;              // 100000
    const int NS   = out_size;                     // 2000

    // workspace layout
    __fp16* Mh = (__fp16*)d_ws;                          // S*F*F halves (2 MB)
    __fp16* Ml = Mh + (size_t)S * F * F;                 // 2 MB
    float* wn  = (float*)(Ml + (size_t)S * F * F);       // S*Msup floats
    int* run   = (int*)(wn + (size_t)S * Msup);          // counters (+pad)
    int* perm  = run + 64;                               // S*N ints

    (void)n_in; (void)ws_size;

    k_zero<<<dim3((NS + 255) / 256), dim3(256), 0, stream>>>(out, NS, run);
    k_rownorm<<<dim3((S * Msup + 3) / 4), dim3(256), 0, stream>>>(sp, w, wn, S * Msup);
    k_scatter<<<dim3((N + 255) / 256), dim3(256), 0, stream>>>(species, run, perm, N);
    k_computeM<<<dim3(F / 64, F / 64, S), dim3(256), 0, stream>>>(sp, wn, Mh, Ml, Msup);
    k_qform<<<dim3((N + QAB - 1) / QAB, 1, S), dim3(256), 0, stream>>>(
        ps, Mh, Ml, perm, run, sid, out, N);
}

// Round 5
// 626.932 us; speedup vs baseline: 1.6793x; 1.0331x over previous
//
#include <hip/hip_runtime.h>
#include <stdint.h>

// SparseGapPerSpecies:
//   e_atom[n] = (x_n^T M_{s(n)} x_n) / ||x_n||^2,  M_s = sum_m (w_m/||y_m||^2) y_m y_m^T
//   energy[struct] = segment_sum(e_atom)
// v4: GEMM-structured split-fp16 MFMA (Z = M * X^T, M symmetric).
//   - v3 was occupancy-capped (256 VGPR x-resident frags -> 1 wave/SIMD, MfmaUtil 20%).
//   - Block: 128 atoms x 128 j, BK=32, jb-loop x4 inside block (X-tile L2 reuse).
//   - acc 128 VGPR (merged cross-product accumulator, exact), ~210 total -> 2 waves/SIMD.
//   - LDS 64KB double-buffered -> 2 blocks/CU. A staged via global_load_lds from
//     pre-arranged [kslot][j][16B] chunks (conflict-free b128 reads, no swizzle needed).
//   - X staged reg-gather + cvt_pkrtz + ds_write (T14 issue-early/write-late).
//   - e and ||x||^2 accumulated per-lane across jb; one atomic pair per atom; k_finalize divides.

#define NFEAT 512
#define NSPEC 4

typedef __fp16 half8 __attribute__((ext_vector_type(8)));
typedef __fp16 half2t __attribute__((ext_vector_type(2)));
typedef float f32x16 __attribute__((ext_vector_type(16)));

#define AS1 __attribute__((address_space(1)))
#define AS3 __attribute__((address_space(3)))

static __device__ __forceinline__ void gload_lds16(const void* g, void* l) {
    __builtin_amdgcn_global_load_lds((const AS1 uint32_t*)g, (AS3 uint32_t*)l, 16, 0, 0);
}

union H2I { half2t h; int i; };
union H8V { half2t h2[4]; half8 h8; int4 i4; };

// ---------------- zero out + counters + per-atom accumulators ----------------
__launch_bounds__(256)
__global__ void k_zero(float* out, int ns, int* run, float* e_acc, float* nrm_acc, int N) {
    int i = blockIdx.x * 256 + threadIdx.x;
    if (i < ns) out[i] = 0.0f;
    if (i < NSPEC) run[i] = 0;
    if (i < N) { e_acc[i] = 0.f; nrm_acc[i] = 0.f; }
}

// ---------------- row inv-norm-weights for support points ----------------
__launch_bounds__(256)
__global__ void k_rownorm(const float* __restrict__ rowsrc, const float* __restrict__ numer,
                          float* __restrict__ dst, int rows) {
    int wv = (blockIdx.x * 256 + threadIdx.x) >> 6;
    int lane = threadIdx.x & 63;
    if (wv >= rows) return;
    const float4* r = (const float4*)(rowsrc + (size_t)wv * NFEAT);
    float4 v0 = r[lane];
    float4 v1 = r[lane + 64];
    float s = v0.x * v0.x + v0.y * v0.y + v0.z * v0.z + v0.w * v0.w
            + v1.x * v1.x + v1.y * v1.y + v1.z * v1.z + v1.w * v1.w;
#pragma unroll
    for (int m = 1; m < 64; m <<= 1) s += __shfl_xor(s, m);
    if (lane == 0) dst[wv] = numer[wv] / s;
}

// ---------------- bucket atoms by species ----------------
__launch_bounds__(256)
__global__ void k_scatter(const int* __restrict__ species, int* __restrict__ run,
                          int* __restrict__ perm, int N) {
    __shared__ int lcnt[NSPEC];
    __shared__ int lbase[NSPEC];
    int t = threadIdx.x;
    if (t < NSPEC) lcnt[t] = 0;
    __syncthreads();
    int n = blockIdx.x * 256 + t;
    int s = 0, li = 0;
    bool valid = (n < N);
    if (valid) {
        s = species[n];
        li = atomicAdd(&lcnt[s], 1);
    }
    __syncthreads();
    if (t < NSPEC) lbase[t] = atomicAdd(&run[t], lcnt[t]);
    __syncthreads();
    if (valid) perm[(size_t)s * N + lbase[s] + li] = n;
}

// ---------------- M_s = A^T diag(wn) A, written as chunked fp16 hi/lo ----------------
// Chunk layout per species: 4 jb x 16 ks chunks of 8192 B.
// Element (r=j-row, c=k-col): byte = s*512K + ((r>>7)*16 + (c>>5))*8192
//                                  + ((c>>3)&3)*2048 + (r&127)*16 + (c&7)*2
#define MK 16
__launch_bounds__(256)
__global__ void k_computeM(const float* __restrict__ sp, const float* __restrict__ wn,
                           __fp16* __restrict__ Ah_g, __fp16* __restrict__ Al_g, int Msup) {
    const int s = blockIdx.z;
    const int i0 = blockIdx.y * 64;
    const int j0 = blockIdx.x * 64;
    __shared__ __align__(16) float As[MK * 64];
    __shared__ __align__(16) float Bs[MK * 64];
    const float* A = sp + (size_t)s * Msup * NFEAT;
    const float* wv = wn + s * Msup;
    const int t = threadIdx.x;
    const int tx = t & 15, ty = t >> 4;
    float acc[4][4] = {{0.f}};
    for (int m0 = 0; m0 < Msup; m0 += MK) {
        __syncthreads();
#pragma unroll
        for (int it = 0; it < 4; ++it) {
            int kt = (t >> 6) * 4 + it;
            int c = t & 63;
            int m = m0 + kt;
            float av = 0.f, bv = 0.f;
            if (m < Msup) {
                av = A[(size_t)m * NFEAT + i0 + c];
                bv = A[(size_t)m * NFEAT + j0 + c] * wv[m];
            }
            As[kt * 64 + c] = av;
            Bs[kt * 64 + c] = bv;
        }
        __syncthreads();
#pragma unroll
        for (int kt = 0; kt < MK; ++kt) {
            float4 a = *(const float4*)&As[kt * 64 + ty * 4];
            float4 b = *(const float4*)&Bs[kt * 64 + tx * 4];
            float aa[4] = {a.x, a.y, a.z, a.w};
            float bb[4] = {b.x, b.y, b.z, b.w};
#pragma unroll
            for (int i = 0; i < 4; ++i)
#pragma unroll
                for (int j = 0; j < 4; ++j) acc[i][j] += aa[i] * bb[j];
        }
    }
    char* Hq = (char*)Ah_g + (size_t)s * 524288;
    char* Lq = (char*)Al_g + (size_t)s * 524288;
#pragma unroll
    for (int i = 0; i < 4; ++i) {
        int r = i0 + ty * 4 + i;
        int c = j0 + tx * 4;
        float a0 = acc[i][0], a1 = acc[i][1], a2 = acc[i][2], a3 = acc[i][3];
        half2t h01 = __builtin_amdgcn_cvt_pkrtz(a0, a1);
        half2t h23 = __builtin_amdgcn_cvt_pkrtz(a2, a3);
        float r0 = (a0 - (float)h01[0]) * 2048.f;
        float r1 = (a1 - (float)h01[1]) * 2048.f;
        float r2 = (a2 - (float)h23[0]) * 2048.f;
        float r3 = (a3 - (float)h23[1]) * 2048.f;
        half2t l01 = __builtin_amdgcn_cvt_pkrtz(r0, r1);
        half2t l23 = __builtin_amdgcn_cvt_pkrtz(r2, r3);
        size_t off = (size_t)((r >> 7) * 16 + (c >> 5)) * 8192
                   + (size_t)(((c >> 3) & 3) * 2048) + (size_t)((r & 127) * 16)
                   + (size_t)((c & 7) * 2);
        H2I c0, c1, c2, c3;
        c0.h = h01; c1.h = h23; c2.h = l01; c3.h = l23;
        int2 hv; hv.x = c0.i; hv.y = c1.i;
        int2 lv; lv.x = c2.i; lv.y = c3.i;
        *(int2*)(Hq + off) = hv;
        *(int2*)(Lq + off) = lv;
    }
}

// ---------------- main: GEMM-structured split-fp16 bilinear form ----------------
// LDS buffer (32KB x2): [0,8K) Ah, [8K,16K) Al, [16K,24K) Bh, [24K,32K) Bl,
// each region [kslot 4][row 128][16B].
__launch_bounds__(256, 2)
__global__ void k_qform(const float* __restrict__ X,
                        const __fp16* __restrict__ Ah_g, const __fp16* __restrict__ Al_g,
                        const int* __restrict__ perm, const int* __restrict__ run,
                        float* __restrict__ e_acc, float* __restrict__ nrm_acc, int N) {
    const int s = blockIdx.z;
    const int cnt = run[s];
    const int p0 = blockIdx.x * 128;
    if (p0 >= cnt) return;
    __shared__ __align__(16) char lds[65536];

    const int t = threadIdx.x;
    const int w = t >> 6;
    const int l = t & 63;
    const int la = l & 31;
    const int g  = l >> 5;
    const int wj = w >> 1;   // j-strip (0..1)
    const int wa = w & 1;    // atom-strip (0..1)

    // this lane's two atoms (C columns / epilogue)
    int idv[2]; bool valid[2];
#pragma unroll
    for (int at = 0; at < 2; ++at) {
        int p = p0 + wa * 64 + at * 32 + la;
        valid[at] = (p < cnt);
        idv[at] = perm[(size_t)s * N + (valid[at] ? p : (cnt - 1))];
    }
    // staging atom for this thread (B-tile gather): atom t>>1, k-half t&1
    const int h = t & 1;
    {
    }
    int pst = p0 + (t >> 1);
    int idst = perm[(size_t)s * N + ((pst < cnt) ? pst : (cnt - 1))];
    const float* xst_base = X + (size_t)idst * NFEAT + h * 16;

    const char* ahb = (const char*)Ah_g + (size_t)s * 524288;
    const char* alb = (const char*)Al_g + (size_t)s * 524288;

    f32x16 z0[2][2] = {{{0.f}}}, zc[2][2] = {{{0.f}}};
    float e_l[2] = {0.f, 0.f}, n_l[2] = {0.f, 0.f};

#define STAGE_A(buf, st_) { \
    char* lb_ = lds + (buf) * 32768; \
    const char* gh_ = ahb + (size_t)(st_) * 8192; \
    const char* gl_ = alb + (size_t)(st_) * 8192; \
    _Pragma("unroll") \
    for (int i_ = 0; i_ < 2; ++i_) { \
        int o_ = w * 2048 + i_ * 1024 + l * 16; \
        gload_lds16(gh_ + o_, lb_ + o_); \
        gload_lds16(gl_ + o_, lb_ + 8192 + o_); \
    } }

#define B_LOAD(st_, vv) { \
    const float* xp_ = xst_base + ((st_) & 15) * 32; \
    vv[0] = *(const float4*)(xp_);      vv[1] = *(const float4*)(xp_ + 4); \
    vv[2] = *(const float4*)(xp_ + 8);  vv[3] = *(const float4*)(xp_ + 12); }

#define B_WRITE(buf, vv) { \
    char* lb_ = lds + (buf) * 32768; \
    float xf_[16] = {vv[0].x, vv[0].y, vv[0].z, vv[0].w,  vv[1].x, vv[1].y, vv[1].z, vv[1].w, \
                     vv[2].x, vv[2].y, vv[2].z, vv[2].w,  vv[3].x, vv[3].y, vv[3].z, vv[3].w}; \
    H8V uh0_, ul0_, uh1_, ul1_; \
    _Pragma("unroll") \
    for (int q_ = 0; q_ < 4; ++q_) { \
        float a_ = xf_[2 * q_], b_ = xf_[2 * q_ + 1]; \
        half2t hp_ = __builtin_amdgcn_cvt_pkrtz(a_, b_); \
        float ra_ = (a_ - (float)hp_[0]) * 2048.f; \
        float rb_ = (b_ - (float)hp_[1]) * 2048.f; \
        uh0_.h2[q_] = hp_; ul0_.h2[q_] = __builtin_amdgcn_cvt_pkrtz(ra_, rb_); \
    } \
    _Pragma("unroll") \
    for (int q_ = 0; q_ < 4; ++q_) { \
        float a_ = xf_[8 + 2 * q_], b_ = xf_[8 + 2 * q_ + 1]; \
        half2t hp_ = __builtin_amdgcn_cvt_pkrtz(a_, b_); \
        float ra_ = (a_ - (float)hp_[0]) * 2048.f; \
        float rb_ = (b_ - (float)hp_[1]) * 2048.f; \
        uh1_.h2[q_] = hp_; ul1_.h2[q_] = __builtin_amdgcn_cvt_pkrtz(ra_, rb_); \
    } \
    int al_ = t >> 1; \
    *(half8*)(lb_ + 16384 + (h * 2    ) * 2048 + al_ * 16) = uh0_.h8; \
    *(half8*)(lb_ + 16384 + (h * 2 + 1) * 2048 + al_ * 16) = uh1_.h8; \
    *(half8*)(lb_ + 24576 + (h * 2    ) * 2048 + al_ * 16) = ul0_.h8; \
    *(half8*)(lb_ + 24576 + (h * 2 + 1) * 2048 + al_ * 16) = ul1_.h8; }

    // prologue: stage st=0 fully
    {
        float4 bv[4];
        B_LOAD(0, bv)
        STAGE_A(0, 0)
        B_WRITE(0, bv)
    }
    __syncthreads();

    for (int st = 0; st < 64; ++st) {
        const int cur = st & 1;
        const int nxt = cur ^ 1;
        float4 bnx[4];
        if (st < 63) {
            B_LOAD(st + 1, bnx)      // issue gather early (T14)
            STAGE_A(nxt, st + 1)     // async global->LDS for M chunk
        }

        // ---- compute K-step on buf cur ----
        const char* bb = lds + cur * 32768;
        __builtin_amdgcn_s_setprio(1);
#pragma unroll
        for (int ki = 0; ki < 2; ++ki) {
            int ksl = ki * 2 + g;
            int ao = ksl * 2048 + (wj * 64 + la) * 16;
            int bo = 16384 + ksl * 2048 + (wa * 64 + la) * 16;
            half8 Ah0 = *(const half8*)(bb + ao);
            half8 Ah1 = *(const half8*)(bb + ao + 512);
            half8 Al0 = *(const half8*)(bb + 8192 + ao);
            half8 Al1 = *(const half8*)(bb + 8192 + ao + 512);
            half8 Bh0 = *(const half8*)(bb + bo);
            half8 Bh1 = *(const half8*)(bb + bo + 512);
            half8 Bl0 = *(const half8*)(bb + 8192 + bo);
            half8 Bl1 = *(const half8*)(bb + 8192 + bo + 512);
            z0[0][0] = __builtin_amdgcn_mfma_f32_32x32x16_f16(Ah0, Bh0, z0[0][0], 0, 0, 0);
            z0[0][1] = __builtin_amdgcn_mfma_f32_32x32x16_f16(Ah0, Bh1, z0[0][1], 0, 0, 0);
            z0[1][0] = __builtin_amdgcn_mfma_f32_32x32x16_f16(Ah1, Bh0, z0[1][0], 0, 0, 0);
            z0[1][1] = __builtin_amdgcn_mfma_f32_32x32x16_f16(Ah1, Bh1, z0[1][1], 0, 0, 0);
            zc[0][0] = __builtin_amdgcn_mfma_f32_32x32x16_f16(Ah0, Bl0, zc[0][0], 0, 0, 0);
            zc[0][1] = __builtin_amdgcn_mfma_f32_32x32x16_f16(Ah0, Bl1, zc[0][1], 0, 0, 0);
            zc[1][0] = __builtin_amdgcn_mfma_f32_32x32x16_f16(Ah1, Bl0, zc[1][0], 0, 0, 0);
            zc[1][1] = __builtin_amdgcn_mfma_f32_32x32x16_f16(Ah1, Bl1, zc[1][1], 0, 0, 0);
            zc[0][0] = __builtin_amdgcn_mfma_f32_32x32x16_f16(Al0, Bh0, zc[0][0], 0, 0, 0);
            zc[0][1] = __builtin_amdgcn_mfma_f32_32x32x16_f16(Al0, Bh1, zc[0][1], 0, 0, 0);
            zc[1][0] = __builtin_amdgcn_mfma_f32_32x32x16_f16(Al1, Bh0, zc[1][0], 0, 0, 0);
            zc[1][1] = __builtin_amdgcn_mfma_f32_32x32x16_f16(Al1, Bh1, zc[1][1], 0, 0, 0);
        }
        __builtin_amdgcn_s_setprio(0);

        // ---- per-jb epilogue fold ----
        if ((st & 15) == 15) {
            const int jb = st >> 4;
#pragma unroll
            for (int at = 0; at < 2; ++at) {
                const float* xr = X + (size_t)idv[at] * NFEAT + jb * 128 + wj * 64 + 4 * g;
#pragma unroll
                for (int jt = 0; jt < 2; ++jt) {
                    float4 x0 = *(const float4*)(xr + jt * 32);
                    float4 x1 = *(const float4*)(xr + jt * 32 + 8);
                    float4 x2 = *(const float4*)(xr + jt * 32 + 16);
                    float4 x3 = *(const float4*)(xr + jt * 32 + 24);
                    float xv[16] = {x0.x, x0.y, x0.z, x0.w,  x1.x, x1.y, x1.z, x1.w,
                                    x2.x, x2.y, x2.z, x2.w,  x3.x, x3.y, x3.z, x3.w};
                    float ee = 0.f, nn = 0.f;
#pragma unroll
                    for (int r = 0; r < 16; ++r) {
                        float zz = z0[jt][at][r] + zc[jt][at][r] * (1.f / 2048.f);
                        ee = fmaf(xv[r], zz, ee);
                        nn = fmaf(xv[r], xv[r], nn);
                    }
                    e_l[at] += ee;
                    n_l[at] += nn;
#pragma unroll
                    for (int r = 0; r < 16; ++r) { z0[jt][at][r] = 0.f; zc[jt][at][r] = 0.f; }
                }
            }
        }

        if (st < 63) B_WRITE(nxt, bnx)   // write-late: cvt + ds_write after compute
        __syncthreads();                 // drains gload_lds (vmcnt) + ds_writes (lgkmcnt)
    }

    // ---- final: combine g-halves, per-atom atomics ----
#pragma unroll
    for (int at = 0; at < 2; ++at) {
        float eg = e_l[at] + __shfl_xor(e_l[at], 32);
        float ng = n_l[at] + __shfl_xor(n_l[at], 32);
        if (g == 0 && valid[at]) {
            atomicAdd(&e_acc[idv[at]], eg);
            atomicAdd(&nrm_acc[idv[at]], ng);
        }
    }
#undef STAGE_A
#undef B_LOAD
#undef B_WRITE
}

// ---------------- finalize: out[sid[n]] += e[n]/nrm[n] ----------------
__launch_bounds__(256)
__global__ void k_finalize(const float* __restrict__ e_acc, const float* __restrict__ nrm_acc,
                           const int* __restrict__ sid, float* __restrict__ out, int N) {
    int n = blockIdx.x * 256 + threadIdx.x;
    if (n < N) atomicAdd(&out[sid[n]], e_acc[n] / nrm_acc[n]);
}

extern "C" void kernel_launch(void* const* d_in, const int* in_sizes, int n_in,
                              void* d_out, int out_size, void* d_ws, size_t ws_size,
                              hipStream_t stream) {
    const float* ps      = (const float*)d_in[0];  // [N, 512]
    const float* sp      = (const float*)d_in[1];  // [4, 1000, 512]
    const float* w       = (const float*)d_in[2];  // [4, 1000]
    const int*   species = (const int*)d_in[3];    // [N]
    const int*   sid     = (const int*)d_in[4];    // [N]
    float* out = (float*)d_out;                    // [n_struct]

    const int S    = NSPEC;
    const int F    = NFEAT;
    const int Msup = in_sizes[2] / S;              // 1000
    const int N    = in_sizes[0] / F;              // 100000
    const int NS   = out_size;                     // 2000

    // workspace layout
    __fp16* Ah = (__fp16*)d_ws;                          // S*F*F halves (2 MB)
    __fp16* Al = Ah + (size_t)S * F * F;                 // 2 MB
    float* wn  = (float*)(Al + (size_t)S * F * F);       // S*Msup floats
    int* run   = (int*)(wn + (size_t)S * Msup);          // counters (+pad)
    int* perm  = run + 64;                               // S*N ints
    float* e_acc   = (float*)(perm + (size_t)S * N);     // N floats
    float* nrm_acc = e_acc + N;                          // N floats

    (void)n_in; (void)ws_size;

    k_zero<<<dim3((N + 255) / 256), dim3(256), 0, stream>>>(out, NS, run, e_acc, nrm_acc, N);
    k_rownorm<<<dim3((S * Msup + 3) / 4), dim3(256), 0, stream>>>(sp, w, wn, S * Msup);
    k_scatter<<<dim3((N + 255) / 256), dim3(256), 0, stream>>>(species, run, perm, N);
    k_computeM<<<dim3(F / 64, F / 64, S), dim3(256), 0, stream>>>(sp, wn, Ah, Al, Msup);
    k_qform<<<dim3((N + 127) / 128, 1, S), dim3(256), 0, stream>>>(
        ps, Ah, Al, perm, run, e_acc, nrm_acc, N);
    k_finalize<<<dim3((N + 255) / 256), dim3(256), 0, stream>>>(e_acc, nrm_acc, sid, out, N);
}